// Round 4
// baseline (623.033 us; speedup 1.0000x reference)
//
#include <hip/hip_runtime.h>
#include <hip/hip_cooperative_groups.h>

namespace cg = cooperative_groups;

// ForgetMult: h_t = f_t*x_t + (1-f_t)*h_{t-1}, shapes (S=4096, B=16, H=512) fp32.
// R7: fused single cooperative kernel. R6 evidence: occupancy 30->55% with dur
// unchanged, VGPR pinned at 36, delivered BW stuck at ~2.6 TB/s => memory-system
// service-rate wall, not occupancy/MLP. Fix = traffic elimination: fuse the
// 3-phase scan with grid.sync() so f,x are read from HBM once (phase-3 re-read
// hits L2/LLC: same block re-reads its own phase-1 tiles in reverse order),
// and out goes out nontemporal. ~700 MB app traffic -> ~415 MB HBM traffic.

#define SQ      4096
#define NC4     2048            // float4 columns = 16*512/4
#define NCH     8192            // scalar chains
#define TT      16              // timesteps per chunk
#define NCHUNK  (SQ / TT)       // 256
#define NTILE   (NCHUNK * 8)    // 2048 tiles (chunk x col-block)

typedef float floatx4 __attribute__((ext_vector_type(4)));

// ---------------- fused cooperative kernel ----------------
__global__ __launch_bounds__(256, 8)
void fm_fused(const float4* __restrict__ f4, const float4* __restrict__ x4,
              const float* __restrict__ h0,
              float4* __restrict__ aggA, float4* __restrict__ aggB,
              float4* __restrict__ out4)
{
  cg::grid_group grid = cg::this_grid();
  const int tid = threadIdx.x;
  const int G   = gridDim.x;

  // ---- Phase 1: per-tile aggregates A = prod(1-f), B = local scan ----
  for (int tile = blockIdx.x; tile < NTILE; tile += G) {
    const int chunk = tile >> 3;
    const int col   = ((tile & 7) << 8) + tid;
    const size_t base = (size_t)(chunk * TT) * NC4 + col;

    float ax = 1.f, ay = 1.f, az = 1.f, aw = 1.f;
    float bx = 0.f, by = 0.f, bz = 0.f, bw = 0.f;
    for (int batch = 0; batch < TT / 8; ++batch) {
      float4 ff[8], xx[8];
#pragma unroll
      for (int i = 0; i < 8; ++i) {
        const size_t idx = base + (size_t)(batch * 8 + i) * NC4;
        ff[i] = f4[idx];
        xx[i] = x4[idx];
      }
#pragma unroll
      for (int i = 0; i < 8; ++i) {
        bx = fmaf(ff[i].x, xx[i].x - bx, bx);
        by = fmaf(ff[i].y, xx[i].y - by, by);
        bz = fmaf(ff[i].z, xx[i].z - bz, bz);
        bw = fmaf(ff[i].w, xx[i].w - bw, bw);
        ax = fmaf(-ff[i].x, ax, ax);
        ay = fmaf(-ff[i].y, ay, ay);
        az = fmaf(-ff[i].z, az, az);
        aw = fmaf(-ff[i].w, aw, aw);
      }
    }
    float4 A; A.x = ax; A.y = ay; A.z = az; A.w = aw;
    float4 B; B.x = bx; B.y = by; B.z = bz; B.w = bw;
    aggA[(size_t)chunk * NC4 + col] = A;
    aggB[(size_t)chunk * NC4 + col] = B;
  }

  grid.sync();

  // ---- Phase 2: middle scan over chunk aggregates (8192 chains) ----
  // hprev written in place into aggB: slot [c][chain] becomes h entering c.
  {
    const int chain = blockIdx.x * 256 + tid;
    if (chain < NCH) {
      const float* __restrict__ As = (const float*)aggA;
      float*                   Bs = (float*)aggB;
      float h = h0[chain];
      for (int cb = 0; cb < NCHUNK / 16; ++cb) {
        float a[16], b[16];
#pragma unroll
        for (int i = 0; i < 16; ++i) {
          const size_t idx = (size_t)(cb * 16 + i) * NCH + chain;
          a[i] = As[idx];
          b[i] = Bs[idx];
        }
#pragma unroll
        for (int i = 0; i < 16; ++i) {
          const size_t idx = (size_t)(cb * 16 + i) * NCH + chain;
          Bs[idx] = h;                 // hprev entering chunk cb*16+i
          h = fmaf(a[i], h, b[i]);
        }
      }
    }
  }

  grid.sync();

  // ---- Phase 3: apply recurrence from hprev (= aggB), reverse tile order ----
  // Same block revisits its own phase-1 tiles (same CU => L2/XCD locality),
  // newest-first so the most-recently-cached tiles hit.
  floatx4* __restrict__ outv = (floatx4*)out4;
  const int kmax = (NTILE - 1 - blockIdx.x) / G;   // last k with tile < NTILE
  for (int k = kmax; k >= 0; --k) {
    const int tile  = blockIdx.x + k * G;
    const int chunk = tile >> 3;
    const int col   = ((tile & 7) << 8) + tid;
    const size_t base = (size_t)(chunk * TT) * NC4 + col;

    float4 h = aggB[(size_t)chunk * NC4 + col];    // hprev
    for (int batch = 0; batch < TT / 8; ++batch) {
      float4 ff[8], xx[8];
#pragma unroll
      for (int i = 0; i < 8; ++i) {
        const size_t idx = base + (size_t)(batch * 8 + i) * NC4;
        ff[i] = f4[idx];
        xx[i] = x4[idx];
      }
#pragma unroll
      for (int i = 0; i < 8; ++i) {
        h.x = fmaf(ff[i].x, xx[i].x - h.x, h.x);
        h.y = fmaf(ff[i].y, xx[i].y - h.y, h.y);
        h.z = fmaf(ff[i].z, xx[i].z - h.z, h.z);
        h.w = fmaf(ff[i].w, xx[i].w - h.w, h.w);
        floatx4 hv; hv.x = h.x; hv.y = h.y; hv.z = h.z; hv.w = h.w;
        __builtin_nontemporal_store(hv, &outv[base + (size_t)(batch * 8 + i) * NC4]);
      }
    }
  }
}

// ---------------- fallback: R6 3-kernel path ----------------
template<int TT_>
__global__ __launch_bounds__(256, 4)
void fm_agg(const float4* __restrict__ f4, const float4* __restrict__ x4,
            float4* __restrict__ aggA, float4* __restrict__ aggB)
{
  const int tid   = threadIdx.x;
  const int chunk = blockIdx.x >> 3;
  const int col   = ((blockIdx.x & 7) << 8) + tid;
  const size_t base = (size_t)(chunk * TT_) * NC4 + col;

  float ax = 1.f, ay = 1.f, az = 1.f, aw = 1.f;
  float bx = 0.f, by = 0.f, bz = 0.f, bw = 0.f;
  for (int batch = 0; batch < TT_ / 8; ++batch) {
    float4 ff[8], xx[8];
#pragma unroll
    for (int i = 0; i < 8; ++i) {
      const size_t idx = base + (size_t)(batch * 8 + i) * NC4;
      ff[i] = f4[idx];
      xx[i] = x4[idx];
    }
#pragma unroll
    for (int i = 0; i < 8; ++i) {
      bx = fmaf(ff[i].x, xx[i].x - bx, bx);
      by = fmaf(ff[i].y, xx[i].y - by, by);
      bz = fmaf(ff[i].z, xx[i].z - bz, bz);
      bw = fmaf(ff[i].w, xx[i].w - bw, bw);
      ax = fmaf(-ff[i].x, ax, ax);
      ay = fmaf(-ff[i].y, ay, ay);
      az = fmaf(-ff[i].z, az, az);
      aw = fmaf(-ff[i].w, aw, aw);
    }
  }
  float4 A; A.x = ax; A.y = ay; A.z = az; A.w = aw;
  float4 B; B.x = bx; B.y = by; B.z = bz; B.w = bw;
  aggA[(size_t)chunk * NC4 + col] = A;
  aggB[(size_t)chunk * NC4 + col] = B;
}

template<int NCHUNK_>
__global__ __launch_bounds__(256, 4)
void fm_mid(const float* __restrict__ A, float* __restrict__ B,
            const float* __restrict__ h0)
{
  const int chain = blockIdx.x * 256 + threadIdx.x;
  float h = h0[chain];
  for (int cb = 0; cb < NCHUNK_ / 16; ++cb) {
    float a[16], b[16];
#pragma unroll
    for (int i = 0; i < 16; ++i) {
      const size_t idx = (size_t)(cb * 16 + i) * NCH + chain;
      a[i] = A[idx];
      b[i] = B[idx];
    }
#pragma unroll
    for (int i = 0; i < 16; ++i) {
      const size_t idx = (size_t)(cb * 16 + i) * NCH + chain;
      B[idx] = h;
      h = fmaf(a[i], h, b[i]);
    }
  }
}

template<int TT_>
__global__ __launch_bounds__(256, 4)
void fm_apply(const float4* __restrict__ f4, const float4* __restrict__ x4,
              const float4* __restrict__ hprev4, float4* __restrict__ out4)
{
  const int NCHUNK_ = SQ / TT_;
  const int tid   = threadIdx.x;
  const int chunk = (NCHUNK_ - 1) - (blockIdx.x >> 3);
  const int col   = ((blockIdx.x & 7) << 8) + tid;
  const size_t base = (size_t)(chunk * TT_) * NC4 + col;

  floatx4* __restrict__ outv = (floatx4*)out4;
  float4 h = hprev4[(size_t)chunk * NC4 + col];
  for (int batch = 0; batch < TT_ / 8; ++batch) {
    float4 ff[8], xx[8];
#pragma unroll
    for (int i = 0; i < 8; ++i) {
      const size_t idx = base + (size_t)(batch * 8 + i) * NC4;
      ff[i] = f4[idx];
      xx[i] = x4[idx];
    }
#pragma unroll
    for (int i = 0; i < 8; ++i) {
      h.x = fmaf(ff[i].x, xx[i].x - h.x, h.x);
      h.y = fmaf(ff[i].y, xx[i].y - h.y, h.y);
      h.z = fmaf(ff[i].z, xx[i].z - h.z, h.z);
      h.w = fmaf(ff[i].w, xx[i].w - h.w, h.w);
      floatx4 hv; hv.x = h.x; hv.y = h.y; hv.z = h.z; hv.w = h.w;
      __builtin_nontemporal_store(hv, &outv[base + (size_t)(batch * 8 + i) * NC4]);
    }
  }
}

__global__ void fm_naive(const float4* __restrict__ f4, const float4* __restrict__ x4,
                         const float4* __restrict__ h04, float4* __restrict__ out4)
{
  const int col = blockIdx.x * blockDim.x + threadIdx.x;
  if (col >= NC4) return;
  float4 h = h04[col];
  for (int t = 0; t < SQ; ++t) {
    const size_t idx = (size_t)t * NC4 + col;
    const float4 ff = f4[idx], xx = x4[idx];
    h.x = fmaf(ff.x, xx.x - h.x, h.x);
    h.y = fmaf(ff.y, xx.y - h.y, h.y);
    h.z = fmaf(ff.z, xx.z - h.z, h.z);
    h.w = fmaf(ff.w, xx.w - h.w, h.w);
    out4[idx] = h;
  }
}

extern "C" void kernel_launch(void* const* d_in, const int* in_sizes, int n_in,
                              void* d_out, int out_size, void* d_ws, size_t ws_size,
                              hipStream_t stream)
{
  const float4* f4  = (const float4*)d_in[0];
  const float4* x4  = (const float4*)d_in[1];
  const float4* h04 = (const float4*)d_in[2];
  float4* out4 = (float4*)d_out;

  const size_t AGG16 = (size_t)NCHUNK * NC4 * 16;      // 8 MB per aggregate array
  const size_t AGG32 = (size_t)(SQ / 32) * NC4 * 16;   // 4 MB

  // One-time host-side capability probe (pure queries, graph-safe, cached).
  static int  coopGrid = -2;   // -2 = unprobed; <=0 = unusable; >0 = grid size
  if (coopGrid == -2) {
    int dev = 0;
    hipGetDevice(&dev);
    hipDeviceProp_t prop;
    int blocksPerCU = 0;
    if (hipGetDeviceProperties(&prop, dev) == hipSuccess &&
        prop.cooperativeLaunch &&
        hipOccupancyMaxActiveBlocksPerMultiprocessor(
            &blocksPerCU, (const void*)fm_fused, 256, 0) == hipSuccess &&
        blocksPerCU > 0) {
      long long g = (long long)blocksPerCU * prop.multiProcessorCount;
      if (g > NTILE) g = NTILE;
      coopGrid = (g >= 32) ? (int)g : 0;   // phase 2 needs >= 32 blocks
    } else {
      coopGrid = 0;
    }
  }

  if (ws_size >= 2 * AGG16 && coopGrid > 0) {
    float4* aggA = (float4*)d_ws;
    float4* aggB = (float4*)((char*)d_ws + AGG16);
    void* args[6];
    args[0] = (void*)&f4;  args[1] = (void*)&x4;  args[2] = (void*)&h04;
    args[3] = (void*)&aggA; args[4] = (void*)&aggB; args[5] = (void*)&out4;
    hipError_t e = hipLaunchCooperativeKernel((const void*)fm_fused,
                                              dim3(coopGrid), dim3(256),
                                              args, 0, stream);
    if (e == hipSuccess) return;
    coopGrid = 0;   // cooperative launch rejected -> permanent fallback
  }

  if (ws_size >= 2 * AGG16) {                          // 16 MB: TT=16 3-kernel
    float4* aggA = (float4*)d_ws;
    float4* aggB = (float4*)((char*)d_ws + AGG16);
    fm_agg<16><<<NTILE, 256, 0, stream>>>(f4, x4, aggA, aggB);
    fm_mid<NCHUNK><<<NCH / 256, 256, 0, stream>>>((const float*)aggA,
                                                  (float*)aggB, (const float*)h04);
    fm_apply<16><<<NTILE, 256, 0, stream>>>(f4, x4, (const float4*)aggB, out4);
  } else if (ws_size >= 2 * AGG32) {                   // 8 MB: TT=32 3-kernel
    float4* aggA = (float4*)d_ws;
    float4* aggB = (float4*)((char*)d_ws + AGG32);
    fm_agg<32><<<(SQ / 32) * 8, 256, 0, stream>>>(f4, x4, aggA, aggB);
    fm_mid<SQ / 32><<<NCH / 256, 256, 0, stream>>>((const float*)aggA,
                                                   (float*)aggB, (const float*)h04);
    fm_apply<32><<<(SQ / 32) * 8, 256, 0, stream>>>(f4, x4, (const float4*)aggB, out4);
  } else {
    fm_naive<<<(NC4 + 255) / 256, 256, 0, stream>>>(f4, x4, h04, out4);
  }
}

// Round 5
// 369.587 us; speedup vs baseline: 1.6858x; 1.6858x over previous
//
#include <hip/hip_runtime.h>

// ForgetMult: h_t = f_t*x_t + (1-f_t)*h_{t-1}, shapes (S=4096, B=16, H=512) fp32.
// R8: contiguous-sweep 3-kernel scan. Evidence so far: per-phase app BW pinned
// at ~2.6 TB/s across 16/32 waves/CU and VGPR 32/36 (R5/R6/R7) => not
// occupancy/MLP-bound; cooperative fusion (R7) lost 370us to grid.sync atomic
// contention. Last structural difference vs the 6.3 TB/s copy ubench: blocks
// here read 4KB then hop 32KB (page-unfriendly, ~2k interleaved streams).
// Fix: block = chunk (grid 256, 512 thr); each block sweeps a contiguous
// 512 KB span of f and x (16 full rows), rows double-buffered in registers
// (t-loop fully unrolled -> static indices, no scratch). K3 same sweep,
// nontemporal contiguous out writes. Math order per column identical to R6.

#define SQ      4096
#define NC4     2048            // float4 columns = 16*512/4
#define NCH     8192            // scalar chains
#define TT      16              // timesteps per chunk
#define NCHUNK  (SQ / TT)       // 256

typedef float floatx4 __attribute__((ext_vector_type(4)));

// ---- K1: per-chunk aggregates A = prod(1-f), B = local scan ----
// Block = chunk. Thread owns 4 float4-columns: col = tid + 512*j.
__global__ __launch_bounds__(512, 1)
void fm_agg(const float4* __restrict__ f4, const float4* __restrict__ x4,
            float4* __restrict__ aggA, float4* __restrict__ aggB)
{
  const int tid   = threadIdx.x;
  const int chunk = blockIdx.x;
  const size_t rowbase = (size_t)chunk * TT * NC4 + tid;

  float4 A[4], B[4];
#pragma unroll
  for (int j = 0; j < 4; ++j) {
    A[j].x = 1.f; A[j].y = 1.f; A[j].z = 1.f; A[j].w = 1.f;
    B[j].x = 0.f; B[j].y = 0.f; B[j].z = 0.f; B[j].w = 0.f;
  }

  float4 ff[2][4], xx[2][4];
#pragma unroll
  for (int j = 0; j < 4; ++j) {
    ff[0][j] = f4[rowbase + 512 * j];
    xx[0][j] = x4[rowbase + 512 * j];
  }

#pragma unroll
  for (int t = 0; t < TT; ++t) {
    const int cur = t & 1, nxt = cur ^ 1;
    if (t + 1 < TT) {
      const size_t r = rowbase + (size_t)(t + 1) * NC4;
#pragma unroll
      for (int j = 0; j < 4; ++j) {
        ff[nxt][j] = f4[r + 512 * j];
        xx[nxt][j] = x4[r + 512 * j];
      }
    }
#pragma unroll
    for (int j = 0; j < 4; ++j) {
      const float4 f_ = ff[cur][j], x_ = xx[cur][j];
      B[j].x = fmaf(f_.x, x_.x - B[j].x, B[j].x);
      B[j].y = fmaf(f_.y, x_.y - B[j].y, B[j].y);
      B[j].z = fmaf(f_.z, x_.z - B[j].z, B[j].z);
      B[j].w = fmaf(f_.w, x_.w - B[j].w, B[j].w);
      A[j].x = fmaf(-f_.x, A[j].x, A[j].x);
      A[j].y = fmaf(-f_.y, A[j].y, A[j].y);
      A[j].z = fmaf(-f_.z, A[j].z, A[j].z);
      A[j].w = fmaf(-f_.w, A[j].w, A[j].w);
    }
  }

#pragma unroll
  for (int j = 0; j < 4; ++j) {
    aggA[(size_t)chunk * NC4 + tid + 512 * j] = A[j];
    aggB[(size_t)chunk * NC4 + tid + 512 * j] = B[j];
  }
}

// ---- K2: scan chunk aggregates per scalar chain, hprev written IN PLACE ----
// Scalar view of aggA/aggB: [chunk][8192 chains]. For each chunk c: read (a,b),
// store incoming h into the B slot (becomes hprev for K3), advance h = a*h+b.
__global__ __launch_bounds__(256, 4)
void fm_mid(const float* __restrict__ A, float* __restrict__ B,
            const float* __restrict__ h0)
{
  const int chain = blockIdx.x * 256 + threadIdx.x;
  float h = h0[chain];
  for (int cb = 0; cb < NCHUNK / 16; ++cb) {
    float a[16], b[16];
#pragma unroll
    for (int i = 0; i < 16; ++i) {
      const size_t idx = (size_t)(cb * 16 + i) * NCH + chain;
      a[i] = A[idx];
      b[i] = B[idx];
    }
#pragma unroll
    for (int i = 0; i < 16; ++i) {
      const size_t idx = (size_t)(cb * 16 + i) * NCH + chain;
      B[idx] = h;                    // hprev entering chunk cb*16+i
      h = fmaf(a[i], h, b[i]);
    }
  }
}

// ---- K3: apply recurrence from hprev (= aggB), contiguous sweep + NT out ----
__global__ __launch_bounds__(512, 1)
void fm_apply(const float4* __restrict__ f4, const float4* __restrict__ x4,
              const float4* __restrict__ hprev4, float4* __restrict__ out4)
{
  const int tid   = threadIdx.x;
  const int chunk = blockIdx.x;
  const size_t rowbase = (size_t)chunk * TT * NC4 + tid;
  floatx4* __restrict__ outv = (floatx4*)out4;

  float4 h[4];
#pragma unroll
  for (int j = 0; j < 4; ++j)
    h[j] = hprev4[(size_t)chunk * NC4 + tid + 512 * j];

  float4 ff[2][4], xx[2][4];
#pragma unroll
  for (int j = 0; j < 4; ++j) {
    ff[0][j] = f4[rowbase + 512 * j];
    xx[0][j] = x4[rowbase + 512 * j];
  }

#pragma unroll
  for (int t = 0; t < TT; ++t) {
    const int cur = t & 1, nxt = cur ^ 1;
    if (t + 1 < TT) {
      const size_t r = rowbase + (size_t)(t + 1) * NC4;
#pragma unroll
      for (int j = 0; j < 4; ++j) {
        ff[nxt][j] = f4[r + 512 * j];
        xx[nxt][j] = x4[r + 512 * j];
      }
    }
    const size_t ro = rowbase + (size_t)t * NC4;
#pragma unroll
    for (int j = 0; j < 4; ++j) {
      const float4 f_ = ff[cur][j], x_ = xx[cur][j];
      h[j].x = fmaf(f_.x, x_.x - h[j].x, h[j].x);
      h[j].y = fmaf(f_.y, x_.y - h[j].y, h[j].y);
      h[j].z = fmaf(f_.z, x_.z - h[j].z, h[j].z);
      h[j].w = fmaf(f_.w, x_.w - h[j].w, h[j].w);
      floatx4 hv; hv.x = h[j].x; hv.y = h[j].y; hv.z = h[j].z; hv.w = h[j].w;
      // Nontemporal: don't let the 128 MB output stream evict f,x from LLC.
      __builtin_nontemporal_store(hv, &outv[ro + 512 * j]);
    }
  }
}

// Fallback (only if ws_size is too small): one float4-column per thread.
__global__ void fm_naive(const float4* __restrict__ f4, const float4* __restrict__ x4,
                         const float4* __restrict__ h04, float4* __restrict__ out4)
{
  const int col = blockIdx.x * blockDim.x + threadIdx.x;
  if (col >= NC4) return;
  float4 h = h04[col];
  for (int t = 0; t < SQ; ++t) {
    const size_t idx = (size_t)t * NC4 + col;
    const float4 ff = f4[idx], xx = x4[idx];
    h.x = fmaf(ff.x, xx.x - h.x, h.x);
    h.y = fmaf(ff.y, xx.y - h.y, h.y);
    h.z = fmaf(ff.z, xx.z - h.z, h.z);
    h.w = fmaf(ff.w, xx.w - h.w, h.w);
    out4[idx] = h;
  }
}

extern "C" void kernel_launch(void* const* d_in, const int* in_sizes, int n_in,
                              void* d_out, int out_size, void* d_ws, size_t ws_size,
                              hipStream_t stream)
{
  const float4* f4  = (const float4*)d_in[0];
  const float4* x4  = (const float4*)d_in[1];
  const float4* h04 = (const float4*)d_in[2];
  float4* out4 = (float4*)d_out;

  const size_t AGG = (size_t)NCHUNK * NC4 * 16;   // 8 MB per aggregate array

  if (ws_size >= 2 * AGG) {                        // 16 MB (proven available, R6)
    float4* aggA = (float4*)d_ws;
    float4* aggB = (float4*)((char*)d_ws + AGG);
    fm_agg<<<NCHUNK, 512, 0, stream>>>(f4, x4, aggA, aggB);
    fm_mid<<<NCH / 256, 256, 0, stream>>>((const float*)aggA,
                                          (float*)aggB, (const float*)h04);
    fm_apply<<<NCHUNK, 512, 0, stream>>>(f4, x4, (const float4*)aggB, out4);
  } else {
    fm_naive<<<(NC4 + 255) / 256, 256, 0, stream>>>(f4, x4, h04, out4);
  }
}